// Round 7
// baseline (133.321 us; speedup 1.0000x reference)
//
#include <hip/hip_runtime.h>
#include <hip/hip_bf16.h>
#include <math.h>

#define TAU_INV_LOG2E 14.4269504088896340736f  // (1/0.1) * log2(e)
#define EPS 1e-8f

typedef __attribute__((ext_vector_type(8))) short bf16x8;
typedef __attribute__((ext_vector_type(4))) float f32x4;

static __device__ __forceinline__ unsigned short f2bf(float f) {
    unsigned int u = __float_as_uint(f);
    unsigned int r = (u + 0x7fffu + ((u >> 16) & 1u)) >> 16;
    return (unsigned short)r;
}

static __device__ __forceinline__ void glds16(const void* g, void* l) {
    __builtin_amdgcn_global_load_lds(
        (const __attribute__((address_space(1))) unsigned int*)g,
        (__attribute__((address_space(3))) unsigned int*)l,
        16, 0, 0);
}

// Kernel 1: L2-normalize rows of x (N x 256 fp32) -> xn (bf16). Zero out[0].
__global__ __launch_bounds__(256) void normalize_kernel(
    const float* __restrict__ x, unsigned short* __restrict__ xn,
    float* __restrict__ out, int N) {
    const int wave = threadIdx.x >> 6;
    const int lane = threadIdx.x & 63;
    const int row  = blockIdx.x * 4 + wave;
    if (row >= N) return;

    if (blockIdx.x == 0 && threadIdx.x == 0) out[0] = 0.0f;

    const float4 v = ((const float4*)(x + (size_t)row * 256))[lane];
    float s = v.x * v.x + v.y * v.y + v.z * v.z + v.w * v.w;
    s += __shfl_xor(s, 1);
    s += __shfl_xor(s, 2);
    s += __shfl_xor(s, 4);
    s += __shfl_xor(s, 8);
    s += __shfl_xor(s, 16);
    s += __shfl_xor(s, 32);
    const float norm = fmaxf(sqrtf(s), 1e-12f);
    const float rinv = 1.0f / norm;

    ushort4 o;
    o.x = f2bf(v.x * rinv);
    o.y = f2bf(v.y * rinv);
    o.z = f2bf(v.z * rinv);
    o.w = f2bf(v.w * rinv);
    ((ushort4*)(xn + (size_t)row * 256))[lane] = o;
}

// Kernel 2: strip GEMM. Block = row-block bi (128 rows) x up to 4 consecutive
// bj tiles (SEG=4, upper triangle) -> 544 blocks. 4 waves, 2M x 2N per tile.
// A (128x256 bf16) loaded ONCE per block into registers (afr, 128 VGPR/wave)
// via a 2-round coalesced+swizzled LDS bounce through the B buffers. B-slices
// (128 j-rows x 64 k = 16 KB) staged per K-step with glds16 into dbuf-2 LDS
// (32 KB total), stage(next) issued before compute (proven r3 schedule).
// This halves LDS-read bytes per MFMA (A reads gone) and amortizes per-block
// fixed costs (decode/prologue/rsum) over ~4 tiles; the per-tile exp epilogue
// overlaps the next tile's staging.
// LDS layout: [128][64] bf16, 16B chunk c of row r stored at c ^ (r&7);
// glds sources pre-swizzled per lane (verified in r6, passed).
// Atomic-free slots:  row-partials -> prowR[2*sid+waveN] (rows of bi)
//                     col-partials -> prowC[2*bi+waveM]  (rows of bj), !diag
__global__ __launch_bounds__(256, 2) void gemm_strip_kernel(
    const unsigned short* __restrict__ xn, float* __restrict__ prowR,
    float* __restrict__ prowC, int N) {
    const int D = 256;
    __shared__ unsigned short Bb[2][128 * 64];  // 2 x 16 KB

    const int tid   = threadIdx.x;
    const int wave  = tid >> 6;
    const int lane  = tid & 63;
    const int waveM = wave >> 1;
    const int waveN = wave & 1;
    const int quad  = lane >> 4;
    const int l16   = lane & 15;

    // decode (bi, sid): strip sid of row-block bi covers bj in [bi+4sid, +4)
    const int B = N >> 7;  // 64
    int rem = blockIdx.x, bi = 0;
    while (rem >= ((B - bi + 3) >> 2)) { rem -= (B - bi + 3) >> 2; ++bi; }
    const int sid    = rem;
    const int bj0    = bi + sid * 4;
    const int ntiles = min(4, B - bj0);
    const int iBase  = bi * 128;

    const int lrow8 = lane >> 3;                 // row within 8-row group
    const int csrc  = (lane & 7) ^ lrow8;        // pre-swizzled src chunk

    auto stage = [&](int buf, int rowBase, int k0) {
        #pragma unroll
        for (int it = 0; it < 4; ++it) {
            const int r = wave * 32 + it * 8 + lrow8;   // 0..127
            glds16(xn + (size_t)(rowBase + r) * D + k0 + csrc * 8,
                   &Bb[buf][(wave * 32 + it * 8) * 64]);
        }
    };

    // ---- A phase: bounce 128x256 A through the two buffers into registers.
    // afr[kc][mt] = A[iBase + waveM*64 + mt*16 + l16][kc*32 + quad*8 .. +7]
    bf16x8 afr[8][4];
    const int arow = waveM * 64 + l16;
    const int rsw  = l16 & 7;   // row&7 for all fragment rows (bases %16==0)

    stage(0, iBase, 0);
    stage(1, iBase, 64);
    __syncthreads();
    #pragma unroll
    for (int h = 0; h < 2; ++h)
        #pragma unroll
        for (int ks = 0; ks < 2; ++ks)
            #pragma unroll
            for (int mt = 0; mt < 4; ++mt)
                afr[h * 2 + ks][mt] = *(const bf16x8*)(
                    &Bb[h][(arow + mt * 16) * 64 + (((ks * 4 + quad) ^ rsw) * 8)]);
    __syncthreads();
    stage(0, iBase, 128);
    stage(1, iBase, 192);
    __syncthreads();
    #pragma unroll
    for (int h = 0; h < 2; ++h)
        #pragma unroll
        for (int ks = 0; ks < 2; ++ks)
            #pragma unroll
            for (int mt = 0; mt < 4; ++mt)
                afr[4 + h * 2 + ks][mt] = *(const bf16x8*)(
                    &Bb[h][(arow + mt * 16) * 64 + (((ks * 4 + quad) ^ rsw) * 8)]);
    __syncthreads();

    // ---- B prologue: first K-slice of first tile into buffer 0
    stage(0, bj0 * 128, 0);
    __syncthreads();

    float rsum[4][4];
    #pragma unroll
    for (int mt = 0; mt < 4; ++mt)
        #pragma unroll
        for (int r = 0; r < 4; ++r) rsum[mt][r] = 0.f;

    const int brow = waveN * 64 + l16;

    for (int t = 0; t < ntiles; ++t) {
        const int bj    = bj0 + t;
        const int jBase = bj * 128;

        f32x4 acc[4][4];
        #pragma unroll
        for (int mt = 0; mt < 4; ++mt)
            #pragma unroll
            for (int nt = 0; nt < 4; ++nt)
                acc[mt][nt] = (f32x4){0.f, 0.f, 0.f, 0.f};

        #pragma unroll
        for (int q = 0; q < 4; ++q) {          // K-step q: k = q*64..+63
            const int cb = q & 1;
            // stage-ahead (issued before compute; drained by next barrier)
            if (q < 3)                 stage(cb ^ 1, jBase, (q + 1) * 64);
            else if (t + 1 < ntiles)   stage(cb ^ 1, jBase + 128, 0);

            #pragma unroll
            for (int ks = 0; ks < 2; ++ks) {
                bf16x8 b[4];
                #pragma unroll
                for (int nt = 0; nt < 4; ++nt)
                    b[nt] = *(const bf16x8*)(
                        &Bb[cb][(brow + nt * 16) * 64 +
                                (((ks * 4 + quad) ^ rsw) * 8)]);
                #pragma unroll
                for (int mt = 0; mt < 4; ++mt)
                    #pragma unroll
                    for (int nt = 0; nt < 4; ++nt)
                        acc[mt][nt] = __builtin_amdgcn_mfma_f32_16x16x32_bf16(
                            afr[q * 2 + ks][mt], b[nt], acc[mt][nt], 0, 0, 0);
            }
            if (q < 3) __syncthreads();
        }

        // per-tile epilogue (register-only + stores); overlaps the staging of
        // the next tile issued at q==3. C/D layout: col=l16, row=quad*4+r.
        float csum[4] = {0.f, 0.f, 0.f, 0.f};
        #pragma unroll
        for (int mt = 0; mt < 4; ++mt) {
            const int gi0 = iBase + waveM * 64 + mt * 16 + quad * 4;
            #pragma unroll
            for (int nt = 0; nt < 4; ++nt) {
                const int gj = jBase + waveN * 64 + nt * 16 + l16;
                #pragma unroll
                for (int r = 0; r < 4; ++r) {
                    float e = __builtin_amdgcn_exp2f(acc[mt][nt][r] * TAU_INV_LOG2E);
                    if (gi0 + r == gj) e = 0.0f;   // diagonal (diag tile only)
                    rsum[mt][r] += e;
                    csum[nt] += e;
                }
            }
        }
        if (bj != bi) {   // col partials (symmetry) -> prowC[2*bi+waveM]
            float* slot = prowC + (size_t)(2 * bi + waveM) * N;
            #pragma unroll
            for (int nt = 0; nt < 4; ++nt) {
                float s = csum[nt];
                s += __shfl_xor(s, 16);
                s += __shfl_xor(s, 32);
                if (quad == 0)
                    slot[jBase + waveN * 64 + nt * 16 + l16] = s;
            }
        }
        if (t + 1 < ntiles) __syncthreads();   // next tile's buffer 0 ready
    }

    // strip row partials -> prowR[2*sid+waveN]
    {
        float* slot = prowR + (size_t)(2 * sid + waveN) * N;
        #pragma unroll
        for (int mt = 0; mt < 4; ++mt) {
            const int gi0 = iBase + waveM * 64 + mt * 16 + quad * 4;
            #pragma unroll
            for (int r = 0; r < 4; ++r) {
                float s = rsum[mt][r];
                s += __shfl_xor(s, 1);
                s += __shfl_xor(s, 2);
                s += __shfl_xor(s, 4);
                s += __shfl_xor(s, 8);
                if (l16 == 0) slot[gi0 + r] = s;
            }
        }
    }
}

// Kernel 3: rowsum_i = valid prowR slots (2*ceil((B-a)/4)) + prowC slots (2a);
// loss += log(rowsum/(N-1)+eps)/N. 32 blocks x 256 threads, one thread/row.
__global__ __launch_bounds__(256) void finalize_kernel(
    const float* __restrict__ prowR, const float* __restrict__ prowC,
    float* __restrict__ out, int N) {
    __shared__ float red[4];
    const int B = N >> 7;
    const int i = blockIdx.x * 256 + threadIdx.x;
    const int a = i >> 7;
    const int nR = 2 * ((B - a + 3) >> 2);
    const int nC = 2 * a;
    float s = 0.f;
    for (int p = 0; p < nR; ++p) s += prowR[(size_t)p * N + i];
    for (int p = 0; p < nC; ++p) s += prowC[(size_t)p * N + i];
    float acc = logf(fmaf(s, 1.0f / (float)(N - 1), EPS));
    acc += __shfl_xor(acc, 1);
    acc += __shfl_xor(acc, 2);
    acc += __shfl_xor(acc, 4);
    acc += __shfl_xor(acc, 8);
    acc += __shfl_xor(acc, 16);
    acc += __shfl_xor(acc, 32);
    const int wave = threadIdx.x >> 6;
    const int lane = threadIdx.x & 63;
    if (lane == 0) red[wave] = acc;
    __syncthreads();
    if (threadIdx.x == 0)
        atomicAdd(out, (red[0] + red[1] + red[2] + red[3]) / (float)N);
}

extern "C" void kernel_launch(void* const* d_in, const int* in_sizes, int n_in,
                              void* d_out, int out_size, void* d_ws, size_t ws_size,
                              hipStream_t stream) {
    const float* x = (const float*)d_in[0];
    const int D = 256;
    const int N = in_sizes[0] / D;  // 8192
    const int B = N / 128;          // 64

    unsigned short* xn = (unsigned short*)d_ws;                 // 4 MB
    float* prowR = (float*)((char*)d_ws + (size_t)N * D * 2);   // 32 x N = 1 MB
    float* prowC = prowR + (size_t)32 * N;                      // 128 x N = 4 MB
    float* out = (float*)d_out;

    normalize_kernel<<<(N + 3) / 4, 256, 0, stream>>>(x, xn, out, N);

    int T = 0;
    for (int bi = 0; bi < B; ++bi) T += (B - bi + 3) >> 2;  // 544 strips
    gemm_strip_kernel<<<T, 256, 0, stream>>>(xn, prowR, prowC, N);

    finalize_kernel<<<N / 256, 256, 0, stream>>>(prowR, prowC, out, N);
}